// Round 7
// baseline (2615.052 us; speedup 1.0000x reference)
//
#include <hip/hip_runtime.h>
#include <hip/hip_bf16.h>
#include <cstdint>
#include <cstddef>
#include <type_traits>

#define B_ALL 256
#define T_LEN 512
#define D_INP 64
#define HD    128
#define G4    512            // 4*H
#define NC    12
#define BCH   128            // batch per chunk
#define ROWS  (BCH * T_LEN)  // 65536 rows per chunk

// ---------- helpers ----------
__device__ __forceinline__ float bf2f(unsigned short u) {
    union { unsigned int i; float f; } v; v.i = ((unsigned int)u) << 16; return v.f;
}
__device__ __forceinline__ unsigned short f2bf(float f) {
    union { float f; unsigned int i; } v; v.f = f;
    unsigned int r = v.i + 0x7FFFu + ((v.i >> 16) & 1u);  // round-nearest-even
    return (unsigned short)(r >> 16);
}
__device__ __forceinline__ float sigf(float x) { return 1.0f / (1.0f + __expf(-x)); }
__device__ __forceinline__ float tanh_f(float x) {
    float xx = fminf(15.0f, fmaxf(-15.0f, x));
    float e = __expf(2.0f * xx);
    return (e - 1.0f) / (e + 1.0f);
}

// LDS-only barrier: drains lgkmcnt but leaves global loads/stores in flight.
#define LDS_BARRIER() asm volatile("s_waitcnt lgkmcnt(0)\n\ts_barrier" ::: "memory")

using bf16x8 = __attribute__((ext_vector_type(8))) short;
using f32x4  = __attribute__((ext_vector_type(4))) float;

// XOR swizzle for [R][32] bf16 LDS tiles (64B rows).
__device__ __forceinline__ int swz(int r, int kb) {
    return (r * 64 + kb) ^ ((r & 3) << 4);
}

// ---------- W split: fp32 -> hi/lo bf16 pair (hi+lo ~ fp32 exact) ----------
__global__ __launch_bounds__(256)
void split_w(const float* __restrict__ w, unsigned short* __restrict__ hi,
             unsigned short* __restrict__ lo, int n)
{
    int i = blockIdx.x * 256 + threadIdx.x;
    if (i < n) {
        float f = w[i];
        unsigned short h = f2bf(f);
        hi[i] = h;
        lo[i] = f2bf(f - bf2f(h));
    }
}

// ---------- gates GEMM (MFMA, split-precision bf16) — unchanged from R3 ----------
template <int TERMS, typename TA>
__global__ __launch_bounds__(256)
void gates_gemm_mfma(const TA* __restrict__ A,
                     const unsigned short* __restrict__ Whi_g,
                     const unsigned short* __restrict__ Wlo_g,
                     const float* __restrict__ bias,
                     const int* __restrict__ lens,
                     unsigned short* __restrict__ out, int K)
{
    int row0 = blockIdx.x * 128;
    int col0 = blockIdx.y * 128;
    int bl = row0 >> 9;
    int t0 = row0 & (T_LEN - 1);
    if (t0 >= lens[bl]) return;

    __shared__ __align__(16) char smem[TERMS == 3 ? 32768 : 24576];
    char* sAhi = smem;                 // [128][32] bf16, swizzled
    char* sWhi = smem + 8192;
    char* sWlo = smem + 16384;
    char* sAlo = (TERMS == 3) ? smem + 24576 : smem;

    int tid = threadIdx.x;
    int l   = tid & 63;
    int w   = tid >> 6;
    int wr  = (w >> 1) * 64;
    int wc  = (w & 1) * 64;

    f32x4 acc[4][4];
#pragma unroll
    for (int mi = 0; mi < 4; ++mi)
#pragma unroll
        for (int ni = 0; ni < 4; ++ni) acc[mi][ni] = (f32x4){0.f, 0.f, 0.f, 0.f};

    int fr = l & 15;
    int fk = (l >> 4) * 16;

    for (int kt = 0; kt < K; kt += 32) {
#pragma unroll
        for (int q = 0; q < 2; ++q) {
            int c = tid + 256 * q;
            int r = c >> 2, kc = c & 3;
            size_t gi = (size_t)(col0 + r) * K + kt + kc * 8;
            *(uint4*)(sWhi + swz(r, kc * 16)) = *(const uint4*)&Whi_g[gi];
            *(uint4*)(sWlo + swz(r, kc * 16)) = *(const uint4*)&Wlo_g[gi];
        }
        if constexpr (std::is_same<TA, unsigned short>::value) {
#pragma unroll
            for (int q = 0; q < 2; ++q) {
                int c = tid + 256 * q;
                int r = c >> 2, kc = c & 3;
                *(uint4*)(sAhi + swz(r, kc * 16)) =
                    *(const uint4*)&A[(size_t)(row0 + r) * K + kt + kc * 8];
            }
        } else {
#pragma unroll
            for (int q = 0; q < 4; ++q) {
                int c = tid + 256 * q;
                int r = c >> 3, kc = c & 7;
                float4 f = *(const float4*)&A[(size_t)(row0 + r) * K + kt + kc * 4];
                ushort4 h, lo;
                h.x = f2bf(f.x); lo.x = f2bf(f.x - bf2f(h.x));
                h.y = f2bf(f.y); lo.y = f2bf(f.y - bf2f(h.y));
                h.z = f2bf(f.z); lo.z = f2bf(f.z - bf2f(h.z));
                h.w = f2bf(f.w); lo.w = f2bf(f.w - bf2f(h.w));
                *(ushort4*)(sAhi + swz(r, kc * 8)) = h;
                *(ushort4*)(sAlo + swz(r, kc * 8)) = lo;
            }
        }
        __syncthreads();

        bf16x8 ah[4], al[4], bh[4], bl4[4];
#pragma unroll
        for (int mi = 0; mi < 4; ++mi) {
            int off = swz(wr + mi * 16 + fr, fk);
            ah[mi] = *(const bf16x8*)(sAhi + off);
            if (TERMS == 3) al[mi] = *(const bf16x8*)(sAlo + off);
        }
#pragma unroll
        for (int ni = 0; ni < 4; ++ni) {
            int off = swz(wc + ni * 16 + fr, fk);
            bh[ni]  = *(const bf16x8*)(sWhi + off);
            bl4[ni] = *(const bf16x8*)(sWlo + off);
        }
#pragma unroll
        for (int mi = 0; mi < 4; ++mi)
#pragma unroll
            for (int ni = 0; ni < 4; ++ni) {
                acc[mi][ni] = __builtin_amdgcn_mfma_f32_16x16x32_bf16(
                    ah[mi], bh[ni], acc[mi][ni], 0, 0, 0);
                acc[mi][ni] = __builtin_amdgcn_mfma_f32_16x16x32_bf16(
                    ah[mi], bl4[ni], acc[mi][ni], 0, 0, 0);
                if (TERMS == 3)
                    acc[mi][ni] = __builtin_amdgcn_mfma_f32_16x16x32_bf16(
                        al[mi], bh[ni], acc[mi][ni], 0, 0, 0);
            }
        __syncthreads();
    }

    int r4 = (l >> 4) * 4;
#pragma unroll
    for (int ni = 0; ni < 4; ++ni) {
        int col = col0 + wc + ni * 16 + fr;
        float bj = bias[col];
#pragma unroll
        for (int mi = 0; mi < 4; ++mi) {
            int row = row0 + wr + mi * 16 + r4;
            f32x4 v = acc[mi][ni];
#pragma unroll
            for (int r = 0; r < 4; ++r)
                out[(size_t)(row + r) * 1024 + col] = f2bf(v[r] + bj);
        }
    }
}

// ---------- LSTM recurrence (R7: ONE barrier/step, per-wave h-slice) ----------
// Dot phase = R3 (tid = ks*128+rr, 4 chains x 32k, gp partials to LDS).
// Delta vs R3:
//  - gp ping-pongs ([2][4][512]) so the nonlin-read of step t and the dot-write
//    of step t+1 never collide -> the 2nd barrier is removed.
//  - the nonlinearity is computed by EVERY wave for the 32-wide h-slice its own
//    dot phase consumes (lane l handles j = ks*32 + (l&31); pair-waves and
//    lane-halves duplicate with identical values - benign). h_s[j] is written
//    by the same wave that reads it next step -> own-wave program order +
//    lgkmcnt replaces the barrier. exp/div work spreads over 8 waves (was 2).
//  - per-j math (gp sum tree, sigf/tanh, xv prefetch) is bit-identical to R3.
__global__ __launch_bounds__(512)
void lstm_rec(const unsigned short* __restrict__ xg,   // [ROWS][1024]
              const float* __restrict__ Whh,           // [2][512][128]
              const int* __restrict__ lens,            // chunk-offset
              unsigned short* __restrict__ hs,         // [ROWS][256] or null
              float* __restrict__ hTf, float* __restrict__ hTb,
              int bOff)
{
    int dir = blockIdx.x >> 7;   // 128 batch per chunk
    int bl  = blockIdx.x & 127;
    int L   = lens[bl];
    int tid = threadIdx.x;
    int ks  = tid >> 7;          // k-quarter 0..3 (wave-uniform)
    int rr  = tid & 127;         // gate row within quarter for the dot phase
    int lane = tid & 63;
    int wid  = tid >> 6;
    int j    = ks * 32 + (lane & 31);          // h index this lane maintains
    bool jlead = ((wid & 1) == 0) && (lane < 32);  // unique owner of j for stores

    __shared__ float h_s[HD];
    __shared__ float gp[2][4][G4];   // ping-pong partial sums

    // w[g][kk] = Whh[dir][g*128 + rr][ks*32 + kk]
    float w[4][32];
#pragma unroll
    for (int g = 0; g < 4; ++g) {
        const float* wrow = Whh + ((size_t)dir * G4 + g * HD + rr) * HD + ks * 32;
#pragma unroll
        for (int k = 0; k < 32; k += 4) {
            float4 v = *(const float4*)(wrow + k);
            w[g][k] = v.x; w[g][k + 1] = v.y; w[g][k + 2] = v.z; w[g][k + 3] = v.w;
        }
    }

    if (tid < HD) h_s[tid] = 0.0f;
    float c = 0.0f, hkeep = 0.0f;
    __syncthreads();

    const unsigned short* xgb = xg + (size_t)bl * T_LEN * 1024 + (size_t)dir * G4;
    int tt   = dir ? (L - 1) : 0;
    int step = dir ? -1 : 1;

    // step-0 gate biases for this lane's j (dup lanes load same addrs: L1 merge)
    float xv0, xv1, xv2, xv3;
    {
        const unsigned short* p = xgb + (size_t)tt * 1024;
        xv0 = bf2f(p[j]);       xv1 = bf2f(p[j + 128]);
        xv2 = bf2f(p[j + 256]); xv3 = bf2f(p[j + 384]);
    }

    int cur = 0;
    for (int t = 0; t < L; ++t) {
        // ---- dot: 4 independent 32-deep chains (reads own-wave h slice) ----
        float a0 = 0.f, a1 = 0.f, a2 = 0.f, a3 = 0.f;
        const float* hq = &h_s[ks * 32];
#pragma unroll
        for (int k = 0; k < 32; k += 4) {
            float4 h4 = *(const float4*)(hq + k);   // wave-uniform broadcast
            a0 += w[0][k] * h4.x + w[0][k+1] * h4.y + w[0][k+2] * h4.z + w[0][k+3] * h4.w;
            a1 += w[1][k] * h4.x + w[1][k+1] * h4.y + w[1][k+2] * h4.z + w[1][k+3] * h4.w;
            a2 += w[2][k] * h4.x + w[2][k+1] * h4.y + w[2][k+2] * h4.z + w[2][k+3] * h4.w;
            a3 += w[3][k] * h4.x + w[3][k+1] * h4.y + w[3][k+2] * h4.z + w[3][k+3] * h4.w;
        }
        gp[cur][ks][rr]       = a0;
        gp[cur][ks][rr + 128] = a1;
        gp[cur][ks][rr + 256] = a2;
        gp[cur][ks][rr + 384] = a3;
        LDS_BARRIER();   // the ONLY barrier: gp-write -> gp-read

        // ---- nonlinearity: every wave computes its own h-slice ----
        float gi = xv0 + ((gp[cur][0][j]       + gp[cur][1][j])       + (gp[cur][2][j]       + gp[cur][3][j]));
        float gf = xv1 + ((gp[cur][0][j + 128] + gp[cur][1][j + 128]) + (gp[cur][2][j + 128] + gp[cur][3][j + 128]));
        float gg = xv2 + ((gp[cur][0][j + 256] + gp[cur][1][j + 256]) + (gp[cur][2][j + 256] + gp[cur][3][j + 256]));
        float go = xv3 + ((gp[cur][0][j + 384] + gp[cur][1][j + 384]) + (gp[cur][2][j + 384] + gp[cur][3][j + 384]));

        // prefetch next step's biases (covered by the rest of this step)
        int ttn = (t + 1 < L) ? (tt + step) : tt;
        {
            const unsigned short* p = xgb + (size_t)ttn * 1024;
            xv0 = bf2f(p[j]);       xv1 = bf2f(p[j + 128]);
            xv2 = bf2f(p[j + 256]); xv3 = bf2f(p[j + 384]);
        }

        float ig = sigf(gi);
        float fg = sigf(gf);
        float G  = tanh_f(gg);
        float og = sigf(go);
        c = fg * c + ig * G;
        float hn = og * tanh_f(c);
        hkeep = hn;

        if (lane < 32) h_s[j] = hn;          // pair-wave dup write: identical value
        if (hs && jlead)
            hs[(size_t)(bl * T_LEN + tt) * 256 + dir * HD + j] = f2bf(hn);

        cur ^= 1;
        tt += step;
        // no second barrier: next dot reads h_s[ks*32..) written by THIS wave.
    }
    if (hTf && jlead) {
        (dir ? hTb : hTf)[(size_t)(bOff + bl) * HD + j] = hkeep;
    }
}

// ---------- final FC + log_softmax ----------
__global__ __launch_bounds__(256)
void fc_lsm(const float* __restrict__ hTf, const float* __restrict__ hTb,
            const float* __restrict__ Wfc, const float* __restrict__ bfc,
            float* __restrict__ out)
{
    int b = threadIdx.x;
    const float* hb = hTb + (size_t)b * HD;
    const float* hf = hTf + (size_t)b * HD;
    float l[NC];
#pragma unroll
    for (int cc = 0; cc < NC; ++cc) {
        const float* wr = Wfc + cc * 256;
        float acc = bfc[cc];
        for (int k = 0; k < HD; k += 4) {
            acc += hb[k] * wr[k] + hb[k + 1] * wr[k + 1]
                 + hb[k + 2] * wr[k + 2] + hb[k + 3] * wr[k + 3];
            acc += hf[k] * wr[128 + k] + hf[k + 1] * wr[128 + k + 1]
                 + hf[k + 2] * wr[128 + k + 2] + hf[k + 3] * wr[128 + k + 3];
        }
        l[cc] = acc;
    }
    float m = l[0];
#pragma unroll
    for (int cc = 1; cc < NC; ++cc) m = fmaxf(m, l[cc]);
    float s = 0.0f;
#pragma unroll
    for (int cc = 0; cc < NC; ++cc) s += __expf(l[cc] - m);
    float lg = m + logf(s);
#pragma unroll
    for (int cc = 0; cc < NC; ++cc) out[(size_t)b * NC + cc] = l[cc] - lg;
}

extern "C" void kernel_launch(void* const* d_in, const int* in_sizes, int n_in,
                              void* d_out, int out_size, void* d_ws, size_t ws_size,
                              hipStream_t stream)
{
    const float* X    = (const float*)d_in[0];
    const int*   len  = (const int*)d_in[1];
    const float* Wih0 = (const float*)d_in[2];   // (2,512,64)  -> (1024,64)
    const float* Whh0 = (const float*)d_in[3];   // (2,512,128)
    const float* b0   = (const float*)d_in[4];   // (2,512) -> (1024)
    const float* Wih1 = (const float*)d_in[5];   // (2,512,256) -> (1024,256)
    const float* Whh1 = (const float*)d_in[6];
    const float* b1   = (const float*)d_in[7];
    const float* Wfc  = (const float*)d_in[8];   // (12,256)
    const float* bfc  = (const float*)d_in[9];   // (12)
    float* out = (float*)d_out;

    char* ws = (char*)d_ws;
    size_t off = 0;
    unsigned short* xg = (unsigned short*)(ws + off); off += (size_t)ROWS * 1024 * 2;
    unsigned short* h1 = (unsigned short*)(ws + off); off += (size_t)ROWS * 256 * 2;
    float* hTf = (float*)(ws + off); off += (size_t)B_ALL * HD * 4;
    float* hTb = (float*)(ws + off); off += (size_t)B_ALL * HD * 4;
    unsigned short* W0hi = (unsigned short*)(ws + off); off += 1024 * 64 * 2;
    unsigned short* W0lo = (unsigned short*)(ws + off); off += 1024 * 64 * 2;
    unsigned short* W1hi = (unsigned short*)(ws + off); off += 1024 * 256 * 2;
    unsigned short* W1lo = (unsigned short*)(ws + off); off += 1024 * 256 * 2;

    split_w<<<(1024 * 64 + 255) / 256, 256, 0, stream>>>(Wih0, W0hi, W0lo, 1024 * 64);
    split_w<<<(1024 * 256 + 255) / 256, 256, 0, stream>>>(Wih1, W1hi, W1lo, 1024 * 256);

    for (int ch = 0; ch < 2; ++ch) {
        const int* lc = len + ch * BCH;
        const float* Xc = X + (size_t)ch * BCH * T_LEN * D_INP;

        gates_gemm_mfma<3, float><<<dim3(ROWS / 128, 8), 256, 0, stream>>>(
            Xc, W0hi, W0lo, b0, lc, xg, D_INP);
        lstm_rec<<<2 * BCH, 512, 0, stream>>>(xg, Whh0, lc, h1,
                                              nullptr, nullptr, 0);
        gates_gemm_mfma<2, unsigned short><<<dim3(ROWS / 128, 8), 256, 0, stream>>>(
            h1, W1hi, W1lo, b1, lc, xg, 2 * HD);
        lstm_rec<<<2 * BCH, 512, 0, stream>>>(xg, Whh1, lc, nullptr,
                                              hTf, hTb, ch * BCH);
    }
    fc_lsm<<<1, 256, 0, stream>>>(hTf, hTb, Wfc, bfc, out);
}

// Round 8
// 2376.448 us; speedup vs baseline: 1.1004x; 1.1004x over previous
//
#include <hip/hip_runtime.h>
#include <hip/hip_bf16.h>
#include <cstdint>
#include <cstddef>
#include <type_traits>

#define B_ALL 256
#define T_LEN 512
#define D_INP 64
#define HD    128
#define G4    512            // 4*H
#define NC    12
#define BCH   128            // batch per chunk
#define ROWS  (BCH * T_LEN)  // 65536 rows per chunk

// ---------- helpers ----------
__device__ __forceinline__ float bf2f(unsigned short u) {
    union { unsigned int i; float f; } v; v.i = ((unsigned int)u) << 16; return v.f;
}
__device__ __forceinline__ unsigned short f2bf(float f) {
    union { float f; unsigned int i; } v; v.f = f;
    unsigned int r = v.i + 0x7FFFu + ((v.i >> 16) & 1u);  // round-nearest-even
    return (unsigned short)(r >> 16);
}
__device__ __forceinline__ float sigf(float x) { return 1.0f / (1.0f + __expf(-x)); }
__device__ __forceinline__ float tanh_f(float x) {
    float xx = fminf(15.0f, fmaxf(-15.0f, x));
    float e = __expf(2.0f * xx);
    return (e - 1.0f) / (e + 1.0f);
}

// LDS-only barrier: drains lgkmcnt but leaves global loads/stores in flight.
#define LDS_BARRIER() asm volatile("s_waitcnt lgkmcnt(0)\n\ts_barrier" ::: "memory")

using bf16x8 = __attribute__((ext_vector_type(8))) short;
using f32x4  = __attribute__((ext_vector_type(4))) float;

// XOR swizzle for [R][32] bf16 LDS tiles (64B rows).
__device__ __forceinline__ int swz(int r, int kb) {
    return (r * 64 + kb) ^ ((r & 3) << 4);
}

// ---------- W split: fp32 -> hi/lo bf16 pair (hi+lo ~ fp32 exact) ----------
__global__ __launch_bounds__(256)
void split_w(const float* __restrict__ w, unsigned short* __restrict__ hi,
             unsigned short* __restrict__ lo, int n)
{
    int i = blockIdx.x * 256 + threadIdx.x;
    if (i < n) {
        float f = w[i];
        unsigned short h = f2bf(f);
        hi[i] = h;
        lo[i] = f2bf(f - bf2f(h));
    }
}

// ---------- gates GEMM (MFMA, split-precision bf16) — unchanged from R3 ----------
template <int TERMS, typename TA>
__global__ __launch_bounds__(256)
void gates_gemm_mfma(const TA* __restrict__ A,
                     const unsigned short* __restrict__ Whi_g,
                     const unsigned short* __restrict__ Wlo_g,
                     const float* __restrict__ bias,
                     const int* __restrict__ lens,
                     unsigned short* __restrict__ out, int K)
{
    int row0 = blockIdx.x * 128;
    int col0 = blockIdx.y * 128;
    int bl = row0 >> 9;
    int t0 = row0 & (T_LEN - 1);
    if (t0 >= lens[bl]) return;

    __shared__ __align__(16) char smem[TERMS == 3 ? 32768 : 24576];
    char* sAhi = smem;                 // [128][32] bf16, swizzled
    char* sWhi = smem + 8192;
    char* sWlo = smem + 16384;
    char* sAlo = (TERMS == 3) ? smem + 24576 : smem;

    int tid = threadIdx.x;
    int l   = tid & 63;
    int w   = tid >> 6;
    int wr  = (w >> 1) * 64;
    int wc  = (w & 1) * 64;

    f32x4 acc[4][4];
#pragma unroll
    for (int mi = 0; mi < 4; ++mi)
#pragma unroll
        for (int ni = 0; ni < 4; ++ni) acc[mi][ni] = (f32x4){0.f, 0.f, 0.f, 0.f};

    int fr = l & 15;
    int fk = (l >> 4) * 16;

    for (int kt = 0; kt < K; kt += 32) {
#pragma unroll
        for (int q = 0; q < 2; ++q) {
            int c = tid + 256 * q;
            int r = c >> 2, kc = c & 3;
            size_t gi = (size_t)(col0 + r) * K + kt + kc * 8;
            *(uint4*)(sWhi + swz(r, kc * 16)) = *(const uint4*)&Whi_g[gi];
            *(uint4*)(sWlo + swz(r, kc * 16)) = *(const uint4*)&Wlo_g[gi];
        }
        if constexpr (std::is_same<TA, unsigned short>::value) {
#pragma unroll
            for (int q = 0; q < 2; ++q) {
                int c = tid + 256 * q;
                int r = c >> 2, kc = c & 3;
                *(uint4*)(sAhi + swz(r, kc * 16)) =
                    *(const uint4*)&A[(size_t)(row0 + r) * K + kt + kc * 8];
            }
        } else {
#pragma unroll
            for (int q = 0; q < 4; ++q) {
                int c = tid + 256 * q;
                int r = c >> 3, kc = c & 7;
                float4 f = *(const float4*)&A[(size_t)(row0 + r) * K + kt + kc * 4];
                ushort4 h, lo;
                h.x = f2bf(f.x); lo.x = f2bf(f.x - bf2f(h.x));
                h.y = f2bf(f.y); lo.y = f2bf(f.y - bf2f(h.y));
                h.z = f2bf(f.z); lo.z = f2bf(f.z - bf2f(h.z));
                h.w = f2bf(f.w); lo.w = f2bf(f.w - bf2f(h.w));
                *(ushort4*)(sAhi + swz(r, kc * 8)) = h;
                *(ushort4*)(sAlo + swz(r, kc * 8)) = lo;
            }
        }
        __syncthreads();

        bf16x8 ah[4], al[4], bh[4], bl4[4];
#pragma unroll
        for (int mi = 0; mi < 4; ++mi) {
            int off = swz(wr + mi * 16 + fr, fk);
            ah[mi] = *(const bf16x8*)(sAhi + off);
            if (TERMS == 3) al[mi] = *(const bf16x8*)(sAlo + off);
        }
#pragma unroll
        for (int ni = 0; ni < 4; ++ni) {
            int off = swz(wc + ni * 16 + fr, fk);
            bh[ni]  = *(const bf16x8*)(sWhi + off);
            bl4[ni] = *(const bf16x8*)(sWlo + off);
        }
#pragma unroll
        for (int mi = 0; mi < 4; ++mi)
#pragma unroll
            for (int ni = 0; ni < 4; ++ni) {
                acc[mi][ni] = __builtin_amdgcn_mfma_f32_16x16x32_bf16(
                    ah[mi], bh[ni], acc[mi][ni], 0, 0, 0);
                acc[mi][ni] = __builtin_amdgcn_mfma_f32_16x16x32_bf16(
                    ah[mi], bl4[ni], acc[mi][ni], 0, 0, 0);
                if (TERMS == 3)
                    acc[mi][ni] = __builtin_amdgcn_mfma_f32_16x16x32_bf16(
                        al[mi], bh[ni], acc[mi][ni], 0, 0, 0);
            }
        __syncthreads();
    }

    int r4 = (l >> 4) * 4;
#pragma unroll
    for (int ni = 0; ni < 4; ++ni) {
        int col = col0 + wc + ni * 16 + fr;
        float bj = bias[col];
#pragma unroll
        for (int mi = 0; mi < 4; ++mi) {
            int row = row0 + wr + mi * 16 + r4;
            f32x4 v = acc[mi][ni];
#pragma unroll
            for (int r = 0; r < 4; ++r)
                out[(size_t)(row + r) * 1024 + col] = f2bf(v[r] + bj);
        }
    }
}

// ---------- LSTM recurrence (R8: 1 barrier, b128 gp, h in registers) ----------
// Dot partition = R3 (tid = ks*128+rr, w[4][32], 4 chains x 32k). Changes:
//  - gpt TRANSPOSED: thread (ks,rr) writes its 4 gate-partials as ONE 16B
//    chunk gpt[ks*128+rr] (1 ds_write_b128/wave, conflict-free). Reader for
//    h-index j needs chunks {ks'*128+j}: 2 ds_read_b128/wave (lane halves
//    take ks'{0,1} / {2,3}); __shfl_xor(32) combines -> (g0+g1)+(g2+g3),
//    the exact R3 reassociation. LDS insts/step: 8w + 16r + 32shfl ~ 56
//    (R3: ~128 incl. 64 b128 broadcast dot-reads).
//  - h never goes through LDS: each wave computes the h-slice it consumes
//    (lane l owns j = ks*32 + (l&31), halves duplicate); next dot reads
//    h[k] via readlane (VALU). One LDS barrier/step (gp visibility); gpt
//    ping-pong kills the cross-step WAR. Nonlin math identical to R3.
__global__ __launch_bounds__(512)
void lstm_rec(const unsigned short* __restrict__ xg,   // [ROWS][1024]
              const float* __restrict__ Whh,           // [2][512][128]
              const int* __restrict__ lens,            // chunk-offset
              unsigned short* __restrict__ hs,         // [ROWS][256] or null
              float* __restrict__ hTf, float* __restrict__ hTb,
              int bOff)
{
    int dir = blockIdx.x >> 7;   // 128 batch per chunk
    int bl  = blockIdx.x & 127;
    int L   = lens[bl];
    int tid = threadIdx.x;
    int ks  = tid >> 7;          // k-quarter 0..3 (wave-pair uniform)
    int rr  = tid & 127;         // gate row within quarter (dot phase)
    int lane = tid & 63;
    int wid  = tid >> 6;
    int j    = ks * 32 + (lane & 31);     // h index this lane maintains
    bool jlead = (lane < 32) && ((wid & 1) == 0);  // unique owner of j
    int sel  = (lane < 32) ? 0 : 2;       // which ks' pair this half reduces

    __shared__ f32x4 gpt[2][G4];          // ping-pong, chunk (ks*128+rr) = 4 gates

    // w[g][kk] = Whh[dir][g*128 + rr][ks*32 + kk]
    float w[4][32];
#pragma unroll
    for (int g = 0; g < 4; ++g) {
        const float* wrow = Whh + ((size_t)dir * G4 + g * HD + rr) * HD + ks * 32;
#pragma unroll
        for (int k = 0; k < 32; k += 4) {
            float4 v = *(const float4*)(wrow + k);
            w[g][k] = v.x; w[g][k + 1] = v.y; w[g][k + 2] = v.z; w[g][k + 3] = v.w;
        }
    }

    float vh = 0.0f;             // h[j], lives in a register
    float c  = 0.0f;

    const unsigned short* xgb = xg + (size_t)bl * T_LEN * 1024 + (size_t)dir * G4;
    int tt   = dir ? (L - 1) : 0;
    int step = dir ? -1 : 1;

    // step-0 gate biases for this lane's j
    float xv0, xv1, xv2, xv3;
    {
        const unsigned short* p = xgb + (size_t)tt * 1024;
        xv0 = bf2f(p[j]);       xv1 = bf2f(p[j + 128]);
        xv2 = bf2f(p[j + 256]); xv3 = bf2f(p[j + 384]);
    }

    int cur = 0;
    for (int t = 0; t < L; ++t) {
        // ---- dot: h[k] via readlane (own-wave register), 4 chains ----
        float a0 = 0.f, a1 = 0.f, a2 = 0.f, a3 = 0.f;
#pragma unroll
        for (int k = 0; k < 32; ++k) {
            float hk = __int_as_float(
                __builtin_amdgcn_readlane(__float_as_int(vh), k));
            a0 = fmaf(w[0][k], hk, a0);
            a1 = fmaf(w[1][k], hk, a1);
            a2 = fmaf(w[2][k], hk, a2);
            a3 = fmaf(w[3][k], hk, a3);
        }
        gpt[cur][ks * 128 + rr] = (f32x4){a0, a1, a2, a3};   // 1 b128 write
        LDS_BARRIER();   // the ONLY barrier: gpt visibility

        // ---- reduce: 2 b128 reads (lane-half split) + shfl combine ----
        f32x4 p0 = gpt[cur][sel * 128 + j];
        f32x4 p1 = gpt[cur][(sel + 1) * 128 + j];
        f32x4 s;
        s.x = p0.x + p1.x; s.y = p0.y + p1.y;
        s.z = p0.z + p1.z; s.w = p0.w + p1.w;
        float o0 = __shfl_xor(s.x, 32);
        float o1 = __shfl_xor(s.y, 32);
        float o2 = __shfl_xor(s.z, 32);
        float o3 = __shfl_xor(s.w, 32);
        float gi = (s.x + o0) + xv0;   // (g0+g1)+(g2+g3): exact R3 order
        float gf = (s.y + o1) + xv1;
        float gg = (s.z + o2) + xv2;
        float go = (s.w + o3) + xv3;

        // prefetch next step's biases (global; in flight across barrier)
        int ttn = (t + 1 < L) ? (tt + step) : tt;
        {
            const unsigned short* p = xgb + (size_t)ttn * 1024;
            xv0 = bf2f(p[j]);       xv1 = bf2f(p[j + 128]);
            xv2 = bf2f(p[j + 256]); xv3 = bf2f(p[j + 384]);
        }

        // ---- nonlinearity (identical math to R3), h stays in vh ----
        float ig = sigf(gi);
        float fg = sigf(gf);
        float G  = tanh_f(gg);
        float og = sigf(go);
        c = fg * c + ig * G;
        float hn = og * tanh_f(c);
        vh = hn;

        if (hs && jlead)
            hs[(size_t)(bl * T_LEN + tt) * 256 + dir * HD + j] = f2bf(hn);

        cur ^= 1;
        tt += step;
        // no second barrier: next dot readlanes vh (own wave); gpt ping-pongs.
    }
    if (hTf && jlead) {
        (dir ? hTb : hTf)[(size_t)(bOff + bl) * HD + j] = vh;
    }
}

// ---------- final FC + log_softmax ----------
__global__ __launch_bounds__(256)
void fc_lsm(const float* __restrict__ hTf, const float* __restrict__ hTb,
            const float* __restrict__ Wfc, const float* __restrict__ bfc,
            float* __restrict__ out)
{
    int b = threadIdx.x;
    const float* hb = hTb + (size_t)b * HD;
    const float* hf = hTf + (size_t)b * HD;
    float l[NC];
#pragma unroll
    for (int cc = 0; cc < NC; ++cc) {
        const float* wr = Wfc + cc * 256;
        float acc = bfc[cc];
        for (int k = 0; k < HD; k += 4) {
            acc += hb[k] * wr[k] + hb[k + 1] * wr[k + 1]
                 + hb[k + 2] * wr[k + 2] + hb[k + 3] * wr[k + 3];
            acc += hf[k] * wr[128 + k] + hf[k + 1] * wr[128 + k + 1]
                 + hf[k + 2] * wr[128 + k + 2] + hf[k + 3] * wr[128 + k + 3];
        }
        l[cc] = acc;
    }
    float m = l[0];
#pragma unroll
    for (int cc = 1; cc < NC; ++cc) m = fmaxf(m, l[cc]);
    float s = 0.0f;
#pragma unroll
    for (int cc = 0; cc < NC; ++cc) s += __expf(l[cc] - m);
    float lg = m + logf(s);
#pragma unroll
    for (int cc = 0; cc < NC; ++cc) out[(size_t)b * NC + cc] = l[cc] - lg;
}

extern "C" void kernel_launch(void* const* d_in, const int* in_sizes, int n_in,
                              void* d_out, int out_size, void* d_ws, size_t ws_size,
                              hipStream_t stream)
{
    const float* X    = (const float*)d_in[0];
    const int*   len  = (const int*)d_in[1];
    const float* Wih0 = (const float*)d_in[2];   // (2,512,64)  -> (1024,64)
    const float* Whh0 = (const float*)d_in[3];   // (2,512,128)
    const float* b0   = (const float*)d_in[4];   // (2,512) -> (1024)
    const float* Wih1 = (const float*)d_in[5];   // (2,512,256) -> (1024,256)
    const float* Whh1 = (const float*)d_in[6];
    const float* b1   = (const float*)d_in[7];
    const float* Wfc  = (const float*)d_in[8];   // (12,256)
    const float* bfc  = (const float*)d_in[9];   // (12)
    float* out = (float*)d_out;

    char* ws = (char*)d_ws;
    size_t off = 0;
    unsigned short* xg = (unsigned short*)(ws + off); off += (size_t)ROWS * 1024 * 2;
    unsigned short* h1 = (unsigned short*)(ws + off); off += (size_t)ROWS * 256 * 2;
    float* hTf = (float*)(ws + off); off += (size_t)B_ALL * HD * 4;
    float* hTb = (float*)(ws + off); off += (size_t)B_ALL * HD * 4;
    unsigned short* W0hi = (unsigned short*)(ws + off); off += 1024 * 64 * 2;
    unsigned short* W0lo = (unsigned short*)(ws + off); off += 1024 * 64 * 2;
    unsigned short* W1hi = (unsigned short*)(ws + off); off += 1024 * 256 * 2;
    unsigned short* W1lo = (unsigned short*)(ws + off); off += 1024 * 256 * 2;

    split_w<<<(1024 * 64 + 255) / 256, 256, 0, stream>>>(Wih0, W0hi, W0lo, 1024 * 64);
    split_w<<<(1024 * 256 + 255) / 256, 256, 0, stream>>>(Wih1, W1hi, W1lo, 1024 * 256);

    for (int ch = 0; ch < 2; ++ch) {
        const int* lc = len + ch * BCH;
        const float* Xc = X + (size_t)ch * BCH * T_LEN * D_INP;

        gates_gemm_mfma<3, float><<<dim3(ROWS / 128, 8), 256, 0, stream>>>(
            Xc, W0hi, W0lo, b0, lc, xg, D_INP);
        lstm_rec<<<2 * BCH, 512, 0, stream>>>(xg, Whh0, lc, h1,
                                              nullptr, nullptr, 0);
        gates_gemm_mfma<2, unsigned short><<<dim3(ROWS / 128, 8), 256, 0, stream>>>(
            h1, W1hi, W1lo, b1, lc, xg, 2 * HD);
        lstm_rec<<<2 * BCH, 512, 0, stream>>>(xg, Whh1, lc, nullptr,
                                              hTf, hTb, ch * BCH);
    }
    fc_lsm<<<1, 256, 0, stream>>>(hTf, hTb, Wfc, bfc, out);
}